// Round 1
// baseline (287.211 us; speedup 1.0000x reference)
//
#include <hip/hip_runtime.h>
#include <hip/hip_cooperative_groups.h>

namespace cg = cooperative_groups;

#define DETN 128
#define NPIX (DETN * DETN)        // 16384 rays per projection
#define VDIM 128
#define NVOX (VDIM * VDIM * VDIM) // 2097152
#define NWORDS (NVOX / 32)        // 65536 words = 256 KiB per bit-volume
#define NSAMP 512
#define SPLITK 4
#define NBLK 1024                 // = 64 ray-blocks x 4 projections x SPLITK

// ---------------------------------------------------------------------------
// Fully fused: zero + backprojection + loss in ONE cooperative launch.
//   phase 0: 262144 threads zero 262144 flag words (1 each) + out
//   phase 1: bp (R2-verified math). Dual-packed bitmaps:
//     frontal (view 0): z-packed  word = ix<<9 | iy<<2 | iz>>5, bit iz&31
//     lateral (view 1): x-packed  word = iz<<9 | iy<<2 | ix>>5, bit ix&31
//     Run-merged bits -> one fire-and-forget atomicOr per ~13 samples.
//   phase 2: loss on 512 blocks (batch split across blocks for 2 blk/CU).
//     Lateral->z-packed via 5-stage __shfl_xor 32x32 bit transpose
//     (replaces the 64-iteration per-thread LDS bit-gather).
// B is fixed at 2 (true for this problem; grid math assumes it).
// __launch_bounds__(256,4): 4 waves/EU -> 4 blocks/CU -> 1024 co-resident. 
// ---------------------------------------------------------------------------
__global__ __launch_bounds__(256, 4) void fused_kernel(
    const float* __restrict__ predF, const float* __restrict__ predL,
    const float* __restrict__ srcF,  const float* __restrict__ srcL,
    const float* __restrict__ tgtF,  const float* __restrict__ tgtL,
    const float* __restrict__ Ainv,  const float* __restrict__ tinv,
    unsigned int* __restrict__ flags,
    const float* __restrict__ gt,
    float* __restrict__ out, float scale)
{
    __shared__ unsigned latw[2][128];   // [yi][z] lateral words, this batch
    __shared__ unsigned fst[256];       // [xi<<3 | yi<<2 | Zi] frontal words
    __shared__ float    smem[4];

    cg::grid_group grid = cg::this_grid();
    const int tid = threadIdx.x;

    // ---------------- phase 0: zero flags (1 word / thread) ----------------
    {
        const int gid = blockIdx.x * 256 + tid;   // NBLK*256 == 4*NWORDS
        flags[gid] = 0u;
        if (gid == 0) *out = 0.0f;
    }
    grid.sync();

    // ---------------- phase 1: backprojection (no early returns) ----------
    {
        const int p    = (blockIdx.x >> 6) & 3;   // projection: view+batch
        const int view = p & 1;
        const int batch= p >> 1;
        const int zs   = blockIdx.x >> 8;         // SPLITK index 0..3
        const int ray  = (blockIdx.x & 63) * 256 + tid;

        const float* mask = (view ? predL : predF) + batch * NPIX;
        if (mask[ray] > 0.5f) {                   // active ray
            const float* src = view ? srcL : srcF;
            const float* tgt = (view ? tgtL : tgtF) + ray * 3;

            const float sx = src[0], sy = src[1], sz = src[2];
            float dx = tgt[0] - sx, dy = tgt[1] - sy, dz = tgt[2] - sz;
            const float len = sqrtf(dx * dx + dy * dy + dz * dz);
            const float inv = 1.0f / (len + 1e-8f);
            dx *= inv; dy *= inv; dz *= inv;

            const float a00 = Ainv[0], a01 = Ainv[1], a02 = Ainv[2];
            const float a10 = Ainv[3], a11 = Ainv[4], a12 = Ainv[5];
            const float a20 = Ainv[6], a21 = Ainv[7], a22 = Ainv[8];
            const float qcx = a00 * sx + a01 * sy + a02 * sz + tinv[0];
            const float qcy = a10 * sx + a11 * sy + a12 * sz + tinv[1];
            const float qcz = a20 * sx + a21 * sy + a22 * sz + tinv[2];
            const float qdx = a00 * dx + a01 * dy + a02 * dz;
            const float qdy = a10 * dx + a11 * dy + a12 * dz;
            const float qdz = a20 * dx + a21 * dy + a22 * dz;

            const float tmax = len * 2.5f;
            const float dt   = tmax * (1.0f / 511.0f);

            float tlo = 0.0f, thi = tmax;
            {
                const float c[3] = {qcx, qcy, qcz};
                const float d[3] = {qdx, qdy, qdz};
                #pragma unroll
                for (int j = 0; j < 3; ++j) {
                    if (fabsf(d[j]) < 1e-8f) {
                        if (c[j] < -0.6f || c[j] > 127.6f) thi = -1.0f;
                    } else {
                        const float ta = (-0.6f  - c[j]) / d[j];
                        const float tb = (127.6f - c[j]) / d[j];
                        tlo = fmaxf(tlo, fminf(ta, tb));
                        thi = fminf(thi, fmaxf(ta, tb));
                    }
                }
            }
            if (tlo <= thi) {
                const int klo = max(0, (int)ceilf(tlo / dt));
                const int khi = min(NSAMP - 1, (int)floorf(thi / dt));
                const int n   = khi - klo + 1;
                const int per = (n + SPLITK - 1) / SPLITK;
                const int k0  = klo + zs * per;
                const int k1  = min(khi, k0 + per - 1);
                if (k0 <= khi) {
                    unsigned int* __restrict__ vol = flags + (size_t)p * NWORDS;
                    int      curw = -1;
                    unsigned bits = 0;
                    for (int k = k0; k <= k1; ++k) {
                        const float t  = (float)k * dt;
                        const float qx = fmaf(qdx, t, qcx);
                        const float qy = fmaf(qdy, t, qcy);
                        const float qz = fmaf(qdz, t, qcz);
                        const int ix = (int)rintf(qx);   // ties-to-even
                        const int iy = (int)rintf(qy);
                        const int iz = (int)rintf(qz);
                        if ((unsigned)ix < (unsigned)VDIM &&
                            (unsigned)iy < (unsigned)VDIM &&
                            (unsigned)iz < (unsigned)VDIM) {
                            const int maj = view ? iz : ix;
                            const int pk  = view ? ix : iz;
                            const int w   = (maj << 9) | (iy << 2) | (pk >> 5);
                            const unsigned bit = 1u << (pk & 31);
                            if (w == curw) {
                                bits |= bit;
                            } else {
                                if (curw >= 0) atomicOr(&vol[curw], bits);
                                curw = w; bits = bit;
                            }
                        }
                    }
                    if (curw >= 0) atomicOr(&vol[curw], bits);
                }
            }
        }
    }
    grid.sync();

    // ---------------- phase 2: loss (512 active blocks, 1 batch each) -----
    if (blockIdx.x < 512) {
        const int b  = blockIdx.x & 1;          // batch
        const int X0 = (blockIdx.x >> 1) & 3;   // x word-group
        const int y0 = (blockIdx.x >> 3) << 1;  // y pair base

        // stage: 256 lateral + 256 frontal words for this batch
        {
            const int yi = tid >> 7;            // lateral: yi = r>>7, z = r&127
            const int z  = tid & 127;
            latw[yi][z] =
                flags[(size_t)(2 * b + 1) * NWORDS + (z << 9) + ((y0 + yi) << 2) + X0];

            const int xi2 = tid >> 3;           // frontal: xi = r>>3, yi, Zi
            const int yi2 = (tid >> 2) & 1;
            const int Zi2 = tid & 3;
            fst[tid] =
                flags[(size_t)(2 * b) * NWORDS + ((32 * X0 + xi2) << 9) +
                      ((y0 + yi2) << 2) + Zi2];
        }
        __syncthreads();

        const int xi   = tid & 31;
        const int yi   = (tid >> 5) & 1;
        const int Zi   = tid >> 6;              // == wave id
        const int lane = tid & 63;

        // 32x32 bit transpose across the 32-lane half (x-packed -> z-packed).
        // Lane l starts with the lateral word for z-sub=l; ends holding the
        // z-packed word for x-sub=l. 5 butterfly stages, branchless selects.
        unsigned W = latw[lane >> 5][(Zi << 5) | (lane & 31)];
        {
            unsigned o;
            o = __shfl_xor(W, 1);
            W = (lane & 1)  ? ((W & 0xAAAAAAAAu) | ((o & 0xAAAAAAAAu) >> 1))
                            : ((W & 0x55555555u) | ((o & 0x55555555u) << 1));
            o = __shfl_xor(W, 2);
            W = (lane & 2)  ? ((W & 0xCCCCCCCCu) | ((o & 0xCCCCCCCCu) >> 2))
                            : ((W & 0x33333333u) | ((o & 0x33333333u) << 2));
            o = __shfl_xor(W, 4);
            W = (lane & 4)  ? ((W & 0xF0F0F0F0u) | ((o & 0xF0F0F0F0u) >> 4))
                            : ((W & 0x0F0F0F0Fu) | ((o & 0x0F0F0F0Fu) << 4));
            o = __shfl_xor(W, 8);
            W = (lane & 8)  ? ((W & 0xFF00FF00u) | ((o & 0xFF00FF00u) >> 8))
                            : ((W & 0x00FF00FFu) | ((o & 0x00FF00FFu) << 8));
            o = __shfl_xor(W, 16);
            W = (lane & 16) ? ((W & 0xFFFF0000u) | ((o & 0xFFFF0000u) >> 16))
                            : ((W & 0x0000FFFFu) | ((o & 0x0000FFFFu) << 16));
        }
        const unsigned L = W;
        const unsigned F = fst[(xi << 3) | (yi << 2) | Zi];

        const int n2 = __popc(F & L);
        const int n1 = __popc(F | L) - n2;
        const int n0 = 32 - n1 - n2;

        const int w = ((32 * X0 + xi) << 9) | ((y0 + yi) << 2) | Zi;
        const float4* __restrict__ g4 = (const float4*)(gt + ((size_t)w << 5));
        float sdot = 0.0f;
        #pragma unroll
        for (int q = 0; q < 8; ++q) {
            const float4 v = g4[q];
            const int i0 = q << 2;
            sdot += v.x * (float)(((F >> (i0 + 0)) & 1u) + ((L >> (i0 + 0)) & 1u));
            sdot += v.y * (float)(((F >> (i0 + 1)) & 1u) + ((L >> (i0 + 1)) & 1u));
            sdot += v.z * (float)(((F >> (i0 + 2)) & 1u) + ((L >> (i0 + 2)) & 1u));
            sdot += v.w * (float)(((F >> (i0 + 3)) & 1u) + ((L >> (i0 + 3)) & 1u));
        }

        float acc = 0.6931471806f * (float)n0 + 1.3132616875f * (float)n1 +
                    2.1269280110f * (float)n2 - sdot;

        // wave reduce (64 lanes) then block reduce, one atomicAdd per block
        #pragma unroll
        for (int off = 32; off > 0; off >>= 1) acc += __shfl_down(acc, off);
        const int wid = tid >> 6;
        if ((tid & 63) == 0) smem[wid] = acc;
        __syncthreads();
        if (tid == 0) {
            const float tot = smem[0] + smem[1] + smem[2] + smem[3];
            atomicAdd(out, tot * scale);
        }
    }
}

extern "C" void kernel_launch(void* const* d_in, const int* in_sizes, int n_in,
                              void* d_out, int out_size, void* d_ws, size_t ws_size,
                              hipStream_t stream) {
    const float* predF = (const float*)d_in[0];
    const float* predL = (const float*)d_in[1];
    const float* srcF  = (const float*)d_in[2];
    const float* tgtF  = (const float*)d_in[3];
    const float* srcL  = (const float*)d_in[4];
    const float* tgtL  = (const float*)d_in[5];
    const float* gt    = (const float*)d_in[6];
    const float* Ainv  = (const float*)d_in[7];
    const float* tinv  = (const float*)d_in[8];

    const int B = in_sizes[0] / NPIX;               // = 2 (grid math assumes)
    unsigned int* flags = (unsigned int*)d_ws;      // 2B bit-volumes, 256 KiB each
    float* outp = (float*)d_out;
    float scale = 1.0f / ((float)NVOX * (float)B);

    void* args[] = {&predF, &predL, &srcF, &srcL, &tgtF, &tgtL,
                    &Ainv, &tinv, &flags, &gt, &outp, &scale};
    hipLaunchCooperativeKernel((void*)fused_kernel, dim3(NBLK), dim3(256),
                               args, 0, stream);
}

// Round 2
// 114.602 us; speedup vs baseline: 2.5062x; 2.5062x over previous
//
#include <hip/hip_runtime.h>

#define DETN 128
#define NPIX (DETN * DETN)        // 16384 rays per projection
#define VDIM 128
#define NVOX (VDIM * VDIM * VDIM) // 2097152
#define NWORDS (NVOX / 32)        // 65536 words = 256 KiB per bit-volume
#define NSAMP 512
#define SPLITK 4

// ---------------------------------------------------------------------------
// Backprojection (R2-verified math, absmax 0.0). Dual-packed bitmaps:
//   frontal (view 0): z-packed  word = ix<<9 | iy<<2 | iz>>5, bit iz&31
//   lateral (view 1): x-packed  word = iz<<9 | iy<<2 | ix>>5, bit ix&31
// Run-merged bits -> one fire-and-forget atomicOr per ~13 samples.
// grid = (NPIX/256, 2B, SPLITK). Also zeroes *out (loss is a later dispatch).
// NOTE: cooperative-launch fusion of these phases was tried (R1) and lost
// ~150us to grid.sync spin-wait across 8 XCDs; keep separate dispatches.
// ---------------------------------------------------------------------------
__global__ __launch_bounds__(256) void bp_kernel(
    const float* __restrict__ predF, const float* __restrict__ predL,
    const float* __restrict__ srcF,  const float* __restrict__ srcL,
    const float* __restrict__ tgtF,  const float* __restrict__ tgtL,
    const float* __restrict__ Ainv,  const float* __restrict__ tinv,
    unsigned int* __restrict__ flags, float* __restrict__ out)
{
    if (blockIdx.x == 0 && blockIdx.y == 0 && blockIdx.z == 0 &&
        threadIdx.x == 0) {
        *out = 0.0f;    // replaces a separate memset dispatch
    }

    const int p     = blockIdx.y;
    const int view  = p & 1;
    const int batch = p >> 1;
    const int ray   = blockIdx.x * blockDim.x + threadIdx.x;

    const float* mask = (view ? predL : predF) + batch * NPIX;
    if (!(mask[ray] > 0.5f)) return;   // inactive ray

    const float* src = view ? srcL : srcF;
    const float* tgt = (view ? tgtL : tgtF) + ray * 3;

    const float sx = src[0], sy = src[1], sz = src[2];
    float dx = tgt[0] - sx, dy = tgt[1] - sy, dz = tgt[2] - sz;
    const float len = sqrtf(dx * dx + dy * dy + dz * dz);
    const float inv = 1.0f / (len + 1e-8f);
    dx *= inv; dy *= inv; dz *= inv;

    // voxel coords affine in t:  q(t) = qc + qd * t
    const float a00 = Ainv[0], a01 = Ainv[1], a02 = Ainv[2];
    const float a10 = Ainv[3], a11 = Ainv[4], a12 = Ainv[5];
    const float a20 = Ainv[6], a21 = Ainv[7], a22 = Ainv[8];
    const float qcx = a00 * sx + a01 * sy + a02 * sz + tinv[0];
    const float qcy = a10 * sx + a11 * sy + a12 * sz + tinv[1];
    const float qcz = a20 * sx + a21 * sy + a22 * sz + tinv[2];
    const float qdx = a00 * dx + a01 * dy + a02 * dz;
    const float qdy = a10 * dx + a11 * dy + a12 * dz;
    const float qdz = a20 * dx + a21 * dy + a22 * dz;

    const float tmax = len * 2.5f;
    const float dt   = tmax * (1.0f / 511.0f);   // t_k = k * dt

    // slab intersection (with margin) to skip out-of-bounds samples
    float tlo = 0.0f, thi = tmax;
    {
        const float c[3] = {qcx, qcy, qcz};
        const float d[3] = {qdx, qdy, qdz};
        #pragma unroll
        for (int j = 0; j < 3; ++j) {
            if (fabsf(d[j]) < 1e-8f) {
                if (c[j] < -0.6f || c[j] > 127.6f) thi = -1.0f;  // empty
            } else {
                const float ta = (-0.6f  - c[j]) / d[j];
                const float tb = (127.6f - c[j]) / d[j];
                tlo = fmaxf(tlo, fminf(ta, tb));
                thi = fminf(thi, fmaxf(ta, tb));
            }
        }
    }
    if (tlo > thi) return;
    const int klo = max(0, (int)ceilf(tlo / dt));
    const int khi = min(NSAMP - 1, (int)floorf(thi / dt));

    // this block-z's k-segment
    const int n   = khi - klo + 1;
    const int per = (n + SPLITK - 1) / SPLITK;
    const int k0  = klo + (int)blockIdx.z * per;
    const int k1  = min(khi, k0 + per - 1);
    if (k0 > khi) return;

    unsigned int* __restrict__ vol = flags + (size_t)p * NWORDS;
    int      curw = -1;
    unsigned bits = 0;
    for (int k = k0; k <= k1; ++k) {
        const float t  = (float)k * dt;
        const float qx = fmaf(qdx, t, qcx);
        const float qy = fmaf(qdy, t, qcy);
        const float qz = fmaf(qdz, t, qcz);
        const int ix = (int)rintf(qx);   // ties-to-even, matches jnp.round
        const int iy = (int)rintf(qy);
        const int iz = (int)rintf(qz);
        if ((unsigned)ix < (unsigned)VDIM && (unsigned)iy < (unsigned)VDIM &&
            (unsigned)iz < (unsigned)VDIM) {
            const int maj = view ? iz : ix;   // slow axis
            const int pk  = view ? ix : iz;   // packed (fast) axis
            const int w   = (maj << 9) | (iy << 2) | (pk >> 5);
            const unsigned bit = 1u << (pk & 31);
            if (w == curw) {
                bits |= bit;
            } else {
                if (curw >= 0) atomicOr(&vol[curw], bits);
                curw = w; bits = bit;
            }
        }
    }
    if (curw >= 0) atomicOr(&vol[curw], bits);
}

// ---------------------------------------------------------------------------
// Loss v3: 512 blocks (one batch each -> 2 blocks/CU), LDS-staged flags,
// gt prefetched to registers BEFORE the staging barrier (overlaps latency),
// lateral x-packed -> z-packed via 5-stage __shfl_xor 32x32 bit transpose
// (bit-exact verified in R1, absmax 0.0; replaces 64-iter LDS bit-gather).
// Block covers batch b, x in [32*X0, 32*X0+32), y in {y0,y0+1}, Z in 0..3
//   -> 256 output words, 1 word (32 voxels)/thread.
// k = bitF + bitL in {0,1,2}; BCE/voxel = -log(1-sigmoid(k)) - g*k.
// B fixed at 2 (grid math assumes it).
// ---------------------------------------------------------------------------
__global__ __launch_bounds__(256) void loss_kernel(
    const unsigned int* __restrict__ flags,
    const float* __restrict__ gt,
    float* __restrict__ out, float scale)
{
    __shared__ unsigned latw[2][128];   // [yi][z] lateral words, this batch
    __shared__ unsigned fst[256];       // [xi<<3 | yi<<2 | Zi] frontal words
    __shared__ float    smem[4];

    const int tid = threadIdx.x;
    const int b   = blockIdx.x & 1;          // batch
    const int X0  = (blockIdx.x >> 1) & 3;   // x word-group
    const int y0  = (blockIdx.x >> 3) << 1;  // y pair base

    const int xi  = tid & 31;
    const int yi  = (tid >> 5) & 1;
    const int Zi  = tid >> 6;                // == wave id
    const int lane = tid & 63;

    // ---- prefetch gt for this thread's output word (no dep on staging) ----
    const int w = ((32 * X0 + xi) << 9) | ((y0 + yi) << 2) | Zi;
    const float4* __restrict__ g4 = (const float4*)(gt + ((size_t)w << 5));
    float4 g[8];
    #pragma unroll
    for (int q = 0; q < 8; ++q) g[q] = g4[q];

    // ---- stage: 256 lateral + 256 frontal words for this batch ----
    {
        const int yiw = tid >> 7;            // lateral: yi = r>>7, z = r&127
        const int z   = tid & 127;
        latw[yiw][z] =
            flags[(size_t)(2 * b + 1) * NWORDS + (z << 9) + ((y0 + yiw) << 2) + X0];

        const int xi2 = tid >> 3;            // frontal: xi = r>>3, yi, Zi
        const int yi2 = (tid >> 2) & 1;
        const int Zi2 = tid & 3;
        fst[tid] =
            flags[(size_t)(2 * b) * NWORDS + ((32 * X0 + xi2) << 9) +
                  ((y0 + yi2) << 2) + Zi2];
    }
    __syncthreads();

    // 32x32 bit transpose across the 32-lane half (x-packed -> z-packed).
    // Lane l starts with the lateral word for z-sub=l; ends holding the
    // z-packed word for x-sub=l. 5 butterfly stages, branchless selects.
    unsigned W = latw[lane >> 5][(Zi << 5) | (lane & 31)];
    {
        unsigned o;
        o = __shfl_xor(W, 1);
        W = (lane & 1)  ? ((W & 0xAAAAAAAAu) | ((o & 0xAAAAAAAAu) >> 1))
                        : ((W & 0x55555555u) | ((o & 0x55555555u) << 1));
        o = __shfl_xor(W, 2);
        W = (lane & 2)  ? ((W & 0xCCCCCCCCu) | ((o & 0xCCCCCCCCu) >> 2))
                        : ((W & 0x33333333u) | ((o & 0x33333333u) << 2));
        o = __shfl_xor(W, 4);
        W = (lane & 4)  ? ((W & 0xF0F0F0F0u) | ((o & 0xF0F0F0F0u) >> 4))
                        : ((W & 0x0F0F0F0Fu) | ((o & 0x0F0F0F0Fu) << 4));
        o = __shfl_xor(W, 8);
        W = (lane & 8)  ? ((W & 0xFF00FF00u) | ((o & 0xFF00FF00u) >> 8))
                        : ((W & 0x00FF00FFu) | ((o & 0x00FF00FFu) << 8));
        o = __shfl_xor(W, 16);
        W = (lane & 16) ? ((W & 0xFFFF0000u) | ((o & 0xFFFF0000u) >> 16))
                        : ((W & 0x0000FFFFu) | ((o & 0x0000FFFFu) << 16));
    }
    const unsigned L = W;
    const unsigned F = fst[(xi << 3) | (yi << 2) | Zi];

    const int n2 = __popc(F & L);
    const int n1 = __popc(F | L) - n2;
    const int n0 = 32 - n1 - n2;

    float sdot = 0.0f;
    #pragma unroll
    for (int q = 0; q < 8; ++q) {
        const int i0 = q << 2;
        sdot += g[q].x * (float)(((F >> (i0 + 0)) & 1u) + ((L >> (i0 + 0)) & 1u));
        sdot += g[q].y * (float)(((F >> (i0 + 1)) & 1u) + ((L >> (i0 + 1)) & 1u));
        sdot += g[q].z * (float)(((F >> (i0 + 2)) & 1u) + ((L >> (i0 + 2)) & 1u));
        sdot += g[q].w * (float)(((F >> (i0 + 3)) & 1u) + ((L >> (i0 + 3)) & 1u));
    }

    float acc = 0.6931471806f * (float)n0 + 1.3132616875f * (float)n1 +
                2.1269280110f * (float)n2 - sdot;

    // wave reduce (64 lanes) then block reduce, one atomicAdd per block
    #pragma unroll
    for (int off = 32; off > 0; off >>= 1) acc += __shfl_down(acc, off);
    const int wid = tid >> 6;
    if ((tid & 63) == 0) smem[wid] = acc;
    __syncthreads();
    if (tid == 0) {
        const float tot = smem[0] + smem[1] + smem[2] + smem[3];
        atomicAdd(out, tot * scale);
    }
}

extern "C" void kernel_launch(void* const* d_in, const int* in_sizes, int n_in,
                              void* d_out, int out_size, void* d_ws, size_t ws_size,
                              hipStream_t stream) {
    const float* predF = (const float*)d_in[0];
    const float* predL = (const float*)d_in[1];
    const float* srcF  = (const float*)d_in[2];
    const float* tgtF  = (const float*)d_in[3];
    const float* srcL  = (const float*)d_in[4];
    const float* tgtL  = (const float*)d_in[5];
    const float* gt    = (const float*)d_in[6];
    const float* Ainv  = (const float*)d_in[7];
    const float* tinv  = (const float*)d_in[8];

    const int B = in_sizes[0] / NPIX;               // = 2
    unsigned int* flags = (unsigned int*)d_ws;      // 2B bit-volumes, 256 KiB each
    float* outp = (float*)d_out;

    hipMemsetAsync(flags, 0, (size_t)(2 * B) * NWORDS * sizeof(unsigned int), stream);

    dim3 gridBp(NPIX / 256, 2 * B, SPLITK);
    bp_kernel<<<gridBp, 256, 0, stream>>>(predF, predL, srcF, srcL,
                                          tgtF, tgtL, Ainv, tinv, flags, outp);

    const float scale = 1.0f / ((float)NVOX * (float)B);
    loss_kernel<<<512, 256, 0, stream>>>(flags, gt, outp, scale);
}